// Round 8
// baseline (258.290 us; speedup 1.0000x reference)
//
#include <hip/hip_runtime.h>
#include <hip/hip_bf16.h>

#define ALPHA 0.2f

typedef __attribute__((ext_vector_type(8))) short short8;
typedef __attribute__((ext_vector_type(4))) float f32x4;

static constexpr int B = 4, N = 2048, F = 256, H = 8, D = 32;
static constexpr int SZ_X = B * N * F, SZ_ADJ = B * N * N, SZ_W = H * F * D, SZ_A = H * 2 * D;

// ws layout (bytes):
// 0        WT   fp32 [hd=256][f=256]   262144   (hd = h*32+d)
// 262144   AF   fp32 [H][64]           2048
// 264192   S1   fp32 [B*H][N]          262144
// 526336   S2   fp32 [B*H][N]          262144
// 788480   S2K  u32  [B*H]             128      (monotone-encoded fp32 max keys)
// 788608   WHT  bf16 [B*H][D][N]       4194304
// 4982912  BM   u64  [B*N*N/64]        2097152  (adjacency bitmask)

__device__ __forceinline__ unsigned pk2(float a, float b) {
    __hip_bfloat16 ha = __float2bfloat16(a), hb = __float2bfloat16(b);
    unsigned short ua = *(unsigned short*)&ha, ub = *(unsigned short*)&hb;
    return (unsigned)ua | ((unsigned)ub << 16);
}

// ---------------- k0: W[h][f][d] -> WT[hd][f]; a -> AF; init S2K -----------
__global__ void k0_prep(const float* __restrict__ Wp, const float* __restrict__ ap,
                        float* __restrict__ WT, float* __restrict__ AF,
                        unsigned* __restrict__ S2K) {
    int bid = blockIdx.x;              // 256 = H*D
    int h = bid >> 5, d = bid & 31;
    int f = threadIdx.x;
    WT[(h * D + d) * F + f] = Wp[(h * F + f) * D + d];
    if (d == 0 && f < 64) AF[h * 64 + f] = ap[h * 64 + f];
    if (bid == 0 && f < 32) S2K[f] = 0u;   // key 0 < encode(any finite float)
}

// ---------------- kbit: adj int32 -> bitmask u64 via ballot ----------------
__global__ void kbit(const int* __restrict__ adj, unsigned long long* __restrict__ bm) {
    // strips of 64 j; 262144 strips; 1024 blocks x 4 waves x 64 iters
    int wgid = blockIdx.x * 4 + (threadIdx.x >> 6);
    int lane = threadIdx.x & 63;
    size_t base = (size_t)wgid * 64;
    for (int it = 0; it < 64; it++) {
        size_t strip = base + it;
        int v = adj[strip * 64 + lane];          // coalesced 4B/lane
        unsigned long long m = __ballot(v != 0); // bit lane <-> j offset
        if (lane == 0) bm[strip] = m;
    }
}

// ---------------- k1: Wh via MFMA; x read ONCE -----------------------------
// block = (b, 32-row n-tile); C[32 n][256 hd]; WHT[bh][d][n] epilogue scatter
__global__ __launch_bounds__(256) void k1_mfma(const float* __restrict__ x,
                                               const float* __restrict__ WT,
                                               __hip_bfloat16* __restrict__ WHT) {
    __shared__ __hip_bfloat16 Abuf[32][264];   // [n][f], pad 264: 2-way banks
    __shared__ __hip_bfloat16 Bbuf[256][40];   // [hd][f-chunk 32], pad 40
    int bid = blockIdx.x;                      // 256 = B*64
    int b = bid >> 6;
    int n0 = (bid & 63) * 32;
    int t = threadIdx.x;

    // stage A: x[32][256] fp32 -> bf16 LDS (read-once; coalesced f32x4)
    {
        int n = t >> 3, g = t & 7;
        const float* xr = x + (size_t)(b * N + n0 + n) * F;
        unsigned* arow = (unsigned*)&Abuf[n][0]; // row byte-base 528: 8B-aligned ok
#pragma unroll
        for (int j = 0; j < 8; j++) {
            int f0 = (g + j * 8) * 4;
            f32x4 v = *(const f32x4*)(xr + f0);
            arow[f0 / 2]     = pk2(v[0], v[1]);
            arow[f0 / 2 + 1] = pk2(v[2], v[3]);
        }
    }

    int lane = t & 63, wave = t >> 6;
    int mt = wave >> 1, nh = wave & 1;
    int lm = lane & 15, lq = lane >> 4;
    f32x4 acc[8] = {};

    for (int kc = 0; kc < 8; kc++) {
        __syncthreads();
        // stage B chunk: WT[hd][kc*32 .. +31] -> Bbuf[hd][0..31]
        {
            const float* wr = WT + (size_t)t * F + kc * 32;
            unsigned* brow = (unsigned*)&Bbuf[t][0];
#pragma unroll
            for (int j = 0; j < 8; j++) {
                f32x4 v = *(const f32x4*)(wr + j * 4);
                brow[j * 2]     = pk2(v[0], v[1]);
                brow[j * 2 + 1] = pk2(v[2], v[3]);
            }
        }
        __syncthreads();
        int k0 = kc * 32 + lq * 8;
        short8 afr = *(const short8*)&Abuf[mt * 16 + lm][k0];
#pragma unroll
        for (int c = 0; c < 8; c++) {
            short8 bfr = *(const short8*)&Bbuf[nh * 128 + c * 16 + lm][lq * 8];
            acc[c] = __builtin_amdgcn_mfma_f32_16x16x32_bf16(afr, bfr, acc[c], 0, 0, 0);
        }
    }
    // epilogue: D[row=n][col=hd] -> WHT[bh][d][n]
#pragma unroll
    for (int c = 0; c < 8; c++) {
        int hd = nh * 128 + c * 16 + lm;
        int h = hd >> 5, d = hd & 31;
        size_t rowb = ((size_t)(b * H + h) * D + d) * N;
#pragma unroll
        for (int r = 0; r < 4; r++) {
            int n = n0 + mt * 16 + lq * 4 + r;
            WHT[rowb + n] = __float2bfloat16(acc[c][r]);
        }
    }
}

// ---------------- k2: s1/s2 per (bh,n); S2K atomic max key -----------------
__global__ void k2_scores(const __hip_bfloat16* __restrict__ WHT,
                          const float* __restrict__ AF,
                          float* __restrict__ S1, float* __restrict__ S2,
                          unsigned* __restrict__ S2K) {
    int bid = blockIdx.x;              // 256 = 32 bh x 8 n-chunks
    int bh = bid >> 3;
    int n = (bid & 7) * 256 + threadIdx.x;
    int h = bh & 7;
    float s1 = 0.f, s2 = 0.f;
#pragma unroll
    for (int d = 0; d < D; d++) {
        float wv = __bfloat162float(WHT[((size_t)bh * D + d) * N + n]);
        s1 += wv * AF[h * 64 + d];
        s2 += wv * AF[h * 64 + 32 + d];
    }
    S1[(size_t)bh * N + n] = s1;
    S2[(size_t)bh * N + n] = s2;
    float mx = s2;
#pragma unroll
    for (int off = 32; off; off >>= 1) mx = fmaxf(mx, __shfl_xor(mx, off));
    __shared__ float wmax[4];
    if ((threadIdx.x & 63) == 0) wmax[threadIdx.x >> 6] = mx;
    __syncthreads();
    if (threadIdx.x == 0) {
        float m = fmaxf(fmaxf(wmax[0], wmax[1]), fmaxf(wmax[2], wmax[3]));
        int bits = __float_as_int(m);
        unsigned key = (unsigned)bits ^ (unsigned)((bits >> 31) | (int)0x80000000);
        atomicMax(S2K + bh, key);      // monotone encode: order-independent
    }
}

// ---------------- k3: fused softmax + P@Wh (MFMA) + ELU --------------------
// grid 1024 = B x 128 i-tiles x 2 head-pairs; wave -> one head; no LDS.
__global__ __launch_bounds__(256) void k3_attn(
    const unsigned* __restrict__ bm,
    const __hip_bfloat16* __restrict__ WHT,
    const float* __restrict__ S1, const float* __restrict__ S2,
    const unsigned* __restrict__ S2K,
    float* __restrict__ out) {
    int bid = blockIdx.x;
    int b = bid >> 8;
    int i0 = ((bid >> 1) & 127) * 16;
    int hp = bid & 1;
    int lane = threadIdx.x & 63, wave = threadIdx.x >> 6;
    int h = hp * 4 + wave;
    int bh = b * H + h;
    int irow = lane & 15, quad = lane >> 4;
    const float C1 = 1.4426950408889634f;      // log2(e)
    const float C2 = ALPHA * C1;

    unsigned key = S2K[bh];
    int mbits = (key & 0x80000000u) ? (int)(key ^ 0x80000000u) : (int)~key;
    float s2max = __int_as_float(mbits);
    float s1i = S1[(size_t)bh * N + i0 + irow];
    float t0 = s1i + s2max;
    float mC = fmaxf(t0, ALPHA * t0) * C1;     // lrelu monotone upper bound, x log2e

    const float* s2p = S2 + (size_t)bh * N;
    const __hip_bfloat16* wb0 = WHT + ((size_t)bh * D + irow) * N;
    const __hip_bfloat16* wb1 = wb0 + (size_t)16 * N;
    const unsigned* bmrow = bm + ((size_t)(b * N) + i0 + irow) * 64;

    f32x4 acc0 = {0.f, 0.f, 0.f, 0.f};
    f32x4 acc1 = {0.f, 0.f, 0.f, 0.f};
    float l = 0.f;
    for (int jb = 0; jb < N; jb += 32) {
        unsigned msk = bmrow[jb >> 5] >> (quad * 8);
        int jo = jb + quad * 8;
        f32x4 sa = *(const f32x4*)(s2p + jo);
        f32x4 sb = *(const f32x4*)(s2p + jo + 4);
        float p[8];
#pragma unroll
        for (int e = 0; e < 8; e++) {
            float s2v = (e < 4) ? sa[e] : sb[e - 4];
            float tt = s1i + s2v;
            // exp(lrelu(tt) - mrow) = exp2(max(tt*C1, tt*C2) - mC), arg <= 0
            float arg = fmaxf(fmaf(tt, C1, -mC), fmaf(tt, C2, -mC));
            float pe = exp2f(arg);
            pe = ((msk >> e) & 1u) ? pe : 0.0f;   // mask -> exact 0
            p[e] = pe;
            l += pe;
        }
        union { short8 s; unsigned u[4]; } af;
        af.u[0] = pk2(p[0], p[1]);
        af.u[1] = pk2(p[2], p[3]);
        af.u[2] = pk2(p[4], p[5]);
        af.u[3] = pk2(p[6], p[7]);
        short8 bf0 = *(const short8*)(wb0 + jo);
        short8 bf1 = *(const short8*)(wb1 + jo);
        acc0 = __builtin_amdgcn_mfma_f32_16x16x32_bf16(af.s, bf0, acc0, 0, 0, 0);
        acc1 = __builtin_amdgcn_mfma_f32_16x16x32_bf16(af.s, bf1, acc1, 0, 0, 0);
    }
    l += __shfl_xor(l, 16);
    l += __shfl_xor(l, 32);
    if (!(l > 0.f)) l = 1.f;
#pragma unroll
    for (int r = 0; r < 4; r++) {
        float lr = __shfl(l, quad * 4 + r);
        float v0 = acc0[r] / lr;
        float v1 = acc1[r] / lr;
        v0 = v0 > 0.f ? v0 : __expf(v0) - 1.f;    // ELU
        v1 = v1 > 0.f ? v1 : __expf(v1) - 1.f;
        size_t rowb = (size_t)(b * N + i0 + quad * 4 + r) * (H * D) + h * D;
        out[rowb + irow] = v0;
        out[rowb + 16 + irow] = v1;
    }
}

extern "C" void kernel_launch(void* const* d_in, const int* in_sizes, int n_in,
                              void* d_out, int out_size, void* d_ws, size_t ws_size,
                              hipStream_t stream) {
    const void *xP = nullptr, *adjP = nullptr, *WP = nullptr, *aP = nullptr;
    for (int i = 0; i < n_in; i++) {
        switch (in_sizes[i]) {
            case SZ_X:   xP = d_in[i]; break;
            case SZ_ADJ: adjP = d_in[i]; break;
            case SZ_W:   WP = d_in[i]; break;
            case SZ_A:   aP = d_in[i]; break;
            default: break;
        }
    }
    if (!xP || !adjP || !WP || !aP) { xP = d_in[0]; adjP = d_in[1]; WP = d_in[2]; aP = d_in[3]; }
    float* out = (float*)d_out;

    char* ws = (char*)d_ws;
    float* WT    = (float*)(ws);
    float* AF    = (float*)(ws + 262144);
    float* S1    = (float*)(ws + 264192);
    float* S2    = (float*)(ws + 526336);
    unsigned* S2K = (unsigned*)(ws + 788480);
    __hip_bfloat16* WHT = (__hip_bfloat16*)(ws + 788608);
    unsigned long long* BM = (unsigned long long*)(ws + 4982912);

    k0_prep<<<256, 256, 0, stream>>>((const float*)WP, (const float*)aP, WT, AF, S2K);
    kbit<<<1024, 256, 0, stream>>>((const int*)adjP, BM);
    k1_mfma<<<256, 256, 0, stream>>>((const float*)xP, WT, WHT);
    k2_scores<<<256, 256, 0, stream>>>(WHT, AF, S1, S2, S2K);
    k3_attn<<<1024, 256, 0, stream>>>((const unsigned*)BM, WHT, S1, S2, S2K, out);
}

// Round 9
// 238.517 us; speedup vs baseline: 1.0829x; 1.0829x over previous
//
#include <hip/hip_runtime.h>
#include <hip/hip_bf16.h>

#define ALPHA 0.2f

typedef __attribute__((ext_vector_type(8))) short short8;
typedef __attribute__((ext_vector_type(4))) float f32x4;

static constexpr int B = 4, N = 2048, F = 256, H = 8, D = 32;
static constexpr int SZ_X = B * N * F, SZ_ADJ = B * N * N, SZ_W = H * F * D, SZ_A = H * 2 * D;

// ws layout (bytes):
// 0        WTbf bf16 [hd=256][f=256]  131072
// 131072   AF   fp32 [H][64]          2048
// 133120   S1   fp32 [B*H][N]         262144
// 395264   UV   fp32 [B*H][N][2]      524288   ({2^(C1*s2), 2^(C2*s2)} pairs)
// 919552   S2K  u32  [B*H]            128      (monotone-encoded fp32 max keys)
// 919680   WHT  bf16 [B*H][D][N]      4194304
// 5113984  BM   u64  [B*N*N/64]       2097152  (adjacency bitmask)  total ~7.2MB

__device__ __forceinline__ unsigned rne16(unsigned u) {
    return u + 0x7fffu + ((u >> 16) & 1u);
}
// pack bf16(a) into low half, bf16(b) into high half
__device__ __forceinline__ unsigned pk_rne(float a, float b) {
    return __builtin_amdgcn_perm(rne16(__float_as_uint(b)),
                                 rne16(__float_as_uint(a)), 0x07060302u);
}
__device__ __forceinline__ unsigned pk_trunc(float a, float b) {
    return __builtin_amdgcn_perm(__float_as_uint(b), __float_as_uint(a), 0x07060302u);
}
__device__ __forceinline__ float bf2f(unsigned short w) {
    return __uint_as_float(((unsigned)w) << 16);
}

// ---- k0: W[h][f][d] -> WTbf[hd][f] (bf16); a -> AF; S2K = 0 ---------------
__global__ void k0_prep(const float* __restrict__ Wp, const float* __restrict__ ap,
                        unsigned short* __restrict__ WTbf, float* __restrict__ AF,
                        unsigned* __restrict__ S2K) {
    int bid = blockIdx.x;              // 256 = H*D
    int h = bid >> 5, d = bid & 31;
    int f = threadIdx.x;
    unsigned u = rne16(__float_as_uint(Wp[(h * F + f) * D + d]));
    WTbf[(h * D + d) * F + f] = (unsigned short)(u >> 16);
    if (d == 0 && f < 64) AF[h * 64 + f] = ap[h * 64 + f];
    if (bid == 0 && f < 32) S2K[f] = 0u;
}

// ---- kbit: adj -> u64 bitmask; 16384 waves x 16 strips, unrolled ----------
__global__ void kbit(const int* __restrict__ adj, unsigned long long* __restrict__ bm) {
    int wid = blockIdx.x * 4 + (threadIdx.x >> 6);   // 4096 blocks
    int lane = threadIdx.x & 63;
    size_t base = (size_t)wid * 16;
#pragma unroll
    for (int s = 0; s < 16; s++) {
        size_t strip = base + s;
        int v = adj[strip * 64 + lane];              // coalesced 4B/lane
        unsigned long long m = __ballot(v != 0);     // bit L <-> j offset L
        if (lane == 0) bm[strip] = m;
    }
}

// ---- k1: Wh via MFMA, LDS-free / sync-free ------------------------------
// 512 blocks = B x 128 16-row tiles; wave w covers hd in [w*64, w*64+64)
__global__ __launch_bounds__(256) void k1_mfma(const float* __restrict__ x,
                                               const unsigned short* __restrict__ WTbf,
                                               unsigned short* __restrict__ WHT) {
    int bid = blockIdx.x;
    int b = bid >> 7, n0 = (bid & 127) * 16;
    int wave = threadIdx.x >> 6, lane = threadIdx.x & 63;
    int lm = lane & 15, lq = lane >> 4;
    const float* xr = x + (size_t)(b * N + n0 + lm) * F;   // A row (L1-shared x4 waves)
    f32x4 acc[4] = {};
#pragma unroll
    for (int kc = 0; kc < 8; kc++) {
        int k0 = kc * 32 + lq * 8;
        f32x4 xa = *(const f32x4*)(xr + k0);
        f32x4 xb = *(const f32x4*)(xr + k0 + 4);
        union { short8 s; unsigned u[4]; } af;
        af.u[0] = pk_rne(xa[0], xa[1]);
        af.u[1] = pk_rne(xa[2], xa[3]);
        af.u[2] = pk_rne(xb[0], xb[1]);
        af.u[3] = pk_rne(xb[2], xb[3]);
#pragma unroll
        for (int c = 0; c < 4; c++) {
            int hd = wave * 64 + c * 16 + lm;
            short8 bf = *(const short8*)(WTbf + hd * F + k0);   // L2-resident
            acc[c] = __builtin_amdgcn_mfma_f32_16x16x32_bf16(af.s, bf, acc[c], 0, 0, 0);
        }
    }
#pragma unroll
    for (int c = 0; c < 4; c++) {
        int hd = wave * 64 + c * 16 + lm;
        int h = hd >> 5, d = hd & 31;
        size_t rowb = ((size_t)(b * H + h) * D + d) * N;
#pragma unroll
        for (int r = 0; r < 4; r++) {
            unsigned u = rne16(__float_as_uint(acc[c][r]));
            WHT[rowb + n0 + lq * 4 + r] = (unsigned short)(u >> 16);   // D[m=lq*4+r][n=lm]
        }
    }
}

// ---- k2: s1 + separable exp factors u,v per (bh,n); S2K atomic max --------
__global__ void k2_scores(const unsigned short* __restrict__ WHT,
                          const float* __restrict__ AF,
                          float* __restrict__ S1, float* __restrict__ UV,
                          unsigned* __restrict__ S2K) {
    int bid = blockIdx.x;              // 256 = 32 bh x 8 n-chunks
    int bh = bid >> 3;
    int n = (bid & 7) * 256 + threadIdx.x;
    int h = bh & 7;
    float s1 = 0.f, s2 = 0.f;
#pragma unroll 8
    for (int d = 0; d < D; d++) {
        float wv = bf2f(WHT[((size_t)bh * D + d) * N + n]);
        s1 += wv * AF[h * 64 + d];
        s2 += wv * AF[h * 64 + 32 + d];
    }
    S1[(size_t)bh * N + n] = s1;
    const float C1 = 1.4426950408889634f, C2 = ALPHA * C1;
    float* uvp = UV + ((size_t)bh * N + n) * 2;
    uvp[0] = exp2f(C1 * s2);
    uvp[1] = exp2f(C2 * s2);
    float mx = s2;
#pragma unroll
    for (int off = 32; off; off >>= 1) mx = fmaxf(mx, __shfl_xor(mx, off));
    __shared__ float wmax[4];
    if ((threadIdx.x & 63) == 0) wmax[threadIdx.x >> 6] = mx;
    __syncthreads();
    if (threadIdx.x == 0) {
        float m = fmaxf(fmaxf(wmax[0], wmax[1]), fmaxf(wmax[2], wmax[3]));
        int bits = __float_as_int(m);
        unsigned key = (unsigned)bits ^ (unsigned)((bits >> 31) | (int)0x80000000);
        atomicMax(S2K + bh, key);
    }
}

// ---- k3: softmax+PV, exp-free inner loop, l via ones-MFMA -----------------
__global__ __launch_bounds__(256) void k3_attn(
    const unsigned* __restrict__ bm,
    const unsigned short* __restrict__ WHT,
    const float* __restrict__ S1, const float* __restrict__ UV,
    const unsigned* __restrict__ S2K,
    float* __restrict__ out) {
    int bid = blockIdx.x;              // 1024 = B x 128 i-tiles x 2 head-pairs
    int b = bid >> 8;
    int i0 = ((bid >> 1) & 127) * 16;
    int hp = bid & 1;
    int lane = threadIdx.x & 63, wave = threadIdx.x >> 6;
    int h = hp * 4 + wave;
    int bh = b * H + h;
    int irow = lane & 15, quad = lane >> 4;
    const float C1 = 1.4426950408889634f, C2 = ALPHA * C1;

    unsigned key = S2K[bh];
    int mbits = (key & 0x80000000u) ? (int)(key ^ 0x80000000u) : (int)~key;
    float s2max = __int_as_float(mbits);
    float s1i = S1[(size_t)bh * N + i0 + irow];
    float t0 = s1i + s2max;
    float mC = fmaxf(t0, ALPHA * t0) * C1;         // C1 * lrelu upper bound
    float ai = exp2f(fmaf(s1i, C1, -mC));          // 2^(C1*s1 - mC)
    float bi = exp2f(fmaf(s1i, C2, -mC));          // 2^(C2*s1 - mC)

    const float* uvp = UV + (size_t)bh * N * 2;
    const unsigned short* wb0 = WHT + ((size_t)bh * D + irow) * N;
    const unsigned short* wb1 = wb0 + (size_t)16 * N;
    const unsigned* bmrow = bm + ((size_t)(b * N) + i0 + irow) * 64;
    const short8 ones = {16256, 16256, 16256, 16256, 16256, 16256, 16256, 16256};

    f32x4 acc0 = {0.f, 0.f, 0.f, 0.f};
    f32x4 acc1 = {0.f, 0.f, 0.f, 0.f};
    f32x4 accL = {0.f, 0.f, 0.f, 0.f};
#pragma unroll 2
    for (int jb = 0; jb < N; jb += 32) {
        unsigned msk = bmrow[jb >> 5] >> (quad * 8);
        int jo = jb + quad * 8;
        const f32x4* up = (const f32x4*)(uvp + jo * 2);
        f32x4 uv0 = up[0], uv1 = up[1], uv2 = up[2], uv3 = up[3];
        // p_j = max(ai*u_j, bi*v_j) = exp(lrelu(s1+s2) - m); masked -> 0
        float p0 = fmaxf(ai * uv0[0], bi * uv0[1]); p0 = (msk & 1u)   ? p0 : 0.f;
        float p1 = fmaxf(ai * uv0[2], bi * uv0[3]); p1 = (msk & 2u)   ? p1 : 0.f;
        float p2 = fmaxf(ai * uv1[0], bi * uv1[1]); p2 = (msk & 4u)   ? p2 : 0.f;
        float p3 = fmaxf(ai * uv1[2], bi * uv1[3]); p3 = (msk & 8u)   ? p3 : 0.f;
        float p4 = fmaxf(ai * uv2[0], bi * uv2[1]); p4 = (msk & 16u)  ? p4 : 0.f;
        float p5 = fmaxf(ai * uv2[2], bi * uv2[3]); p5 = (msk & 32u)  ? p5 : 0.f;
        float p6 = fmaxf(ai * uv3[0], bi * uv3[1]); p6 = (msk & 64u)  ? p6 : 0.f;
        float p7 = fmaxf(ai * uv3[2], bi * uv3[3]); p7 = (msk & 128u) ? p7 : 0.f;
        union { short8 s; unsigned u[4]; } af;
        af.u[0] = pk_trunc(p0, p1);
        af.u[1] = pk_trunc(p2, p3);
        af.u[2] = pk_trunc(p4, p5);
        af.u[3] = pk_trunc(p6, p7);
        short8 bf0 = *(const short8*)(wb0 + jo);
        short8 bf1 = *(const short8*)(wb1 + jo);
        acc0 = __builtin_amdgcn_mfma_f32_16x16x32_bf16(af.s, bf0, acc0, 0, 0, 0);
        acc1 = __builtin_amdgcn_mfma_f32_16x16x32_bf16(af.s, bf1, acc1, 0, 0, 0);
        accL = __builtin_amdgcn_mfma_f32_16x16x32_bf16(af.s, ones, accL, 0, 0, 0);
    }
    // accL[r] = row-sum l for i = quad*4+r (same value in every column lane)
#pragma unroll
    for (int r = 0; r < 4; r++) {
        float lr = accL[r];
        float rin = 1.0f / (lr > 0.f ? lr : 1.f);
        float v0 = acc0[r] * rin;
        float v1 = acc1[r] * rin;
        v0 = v0 > 0.f ? v0 : __expf(v0) - 1.f;     // ELU
        v1 = v1 > 0.f ? v1 : __expf(v1) - 1.f;
        size_t rowb = (size_t)(b * N + i0 + quad * 4 + r) * (H * D) + h * D;
        out[rowb + irow] = v0;
        out[rowb + 16 + irow] = v1;
    }
}

extern "C" void kernel_launch(void* const* d_in, const int* in_sizes, int n_in,
                              void* d_out, int out_size, void* d_ws, size_t ws_size,
                              hipStream_t stream) {
    const void *xP = nullptr, *adjP = nullptr, *WP = nullptr, *aP = nullptr;
    for (int i = 0; i < n_in; i++) {
        switch (in_sizes[i]) {
            case SZ_X:   xP = d_in[i]; break;
            case SZ_ADJ: adjP = d_in[i]; break;
            case SZ_W:   WP = d_in[i]; break;
            case SZ_A:   aP = d_in[i]; break;
            default: break;
        }
    }
    if (!xP || !adjP || !WP || !aP) { xP = d_in[0]; adjP = d_in[1]; WP = d_in[2]; aP = d_in[3]; }
    float* out = (float*)d_out;

    char* ws = (char*)d_ws;
    unsigned short* WTbf = (unsigned short*)(ws);
    float* AF     = (float*)(ws + 131072);
    float* S1     = (float*)(ws + 133120);
    float* UV     = (float*)(ws + 395264);
    unsigned* S2K = (unsigned*)(ws + 919552);
    unsigned short* WHT = (unsigned short*)(ws + 919680);
    unsigned long long* BM = (unsigned long long*)(ws + 5113984);

    k0_prep<<<256, 256, 0, stream>>>((const float*)WP, (const float*)aP, WTbf, AF, S2K);
    kbit<<<4096, 256, 0, stream>>>((const int*)adjP, BM);
    k1_mfma<<<512, 256, 0, stream>>>((const float*)xP, WTbf, WHT);
    k2_scores<<<256, 256, 0, stream>>>(WHT, AF, S1, UV, S2K);
    k3_attn<<<1024, 256, 0, stream>>>((const unsigned*)BM, WHT, S1, UV, S2K, out);
}

// Round 11
// 224.506 us; speedup vs baseline: 1.1505x; 1.0624x over previous
//
#include <hip/hip_runtime.h>
#include <hip/hip_bf16.h>

#define ALPHA 0.2f

typedef __attribute__((ext_vector_type(8))) short short8;
typedef __attribute__((ext_vector_type(8))) _Float16 h8;
typedef __attribute__((ext_vector_type(2))) _Float16 h2v;
typedef __attribute__((ext_vector_type(4))) float f32x4;

static constexpr int B = 4, N = 2048, F = 256, H = 8, D = 32;
static constexpr int SZ_X = B * N * F, SZ_ADJ = B * N * N, SZ_W = H * F * D, SZ_A = H * 2 * D;
static const float C1 = 1.4426950408889634f;           // log2(e)
static const float C2 = ALPHA * 1.4426950408889634f;

// ws layout (bytes):
// 0        WTbf bf16 [hd=256][f=256]  131072
// 131072   AF   f32  [H][64]          2048
// 133120   S1   f32  [32][2048]       262144
// 395264   UH   f16  [32][2048]       131072   u_j = 2^(C1*s2_j)
// 526336   VH   f16  [32][2048]       131072   v_j = 2^(C2*s2_j)
// 657408   WHH  f16  [32][32][2048]   4194304
// 4851712  MSK  u8   [B*N*N]          16777216 (byte path; 0x3C = f16 1.0 hi-byte)
//    or    BM   u64  [B*N*N/64]       2097152  (bit fallback if ws too small)

__device__ __forceinline__ unsigned rne16(unsigned u) {
    return u + 0x7fffu + ((u >> 16) & 1u);
}
__device__ __forceinline__ unsigned pk_rne(float a, float b) {   // bf16 pair
    return __builtin_amdgcn_perm(rne16(__float_as_uint(b)),
                                 rne16(__float_as_uint(a)), 0x07060302u);
}
__device__ __forceinline__ unsigned h2mul(unsigned a, unsigned b) {
    h2v r = __builtin_bit_cast(h2v, a) * __builtin_bit_cast(h2v, b);
    return __builtin_bit_cast(unsigned, r);
}
__device__ __forceinline__ unsigned h2max(unsigned a, unsigned b) {
    h2v r = __builtin_elementwise_max(__builtin_bit_cast(h2v, a),
                                      __builtin_bit_cast(h2v, b));
    return __builtin_bit_cast(unsigned, r);
}

// ---- k0: W[h][f][d] -> WTbf[hd][f] bf16; a -> AF --------------------------
__global__ void k0_prep(const float* __restrict__ Wp, const float* __restrict__ ap,
                        unsigned short* __restrict__ WTbf, float* __restrict__ AF) {
    int bid = blockIdx.x;              // 256 = H*D
    int h = bid >> 5, d = bid & 31;
    int f = threadIdx.x;
    WTbf[(h * D + d) * F + f] =
        (unsigned short)(rne16(__float_as_uint(Wp[(h * F + f) * D + d])) >> 16);
    if (d == 0 && f < 64) AF[h * 64 + f] = ap[h * 64 + f];
}

// ---- kmask: adj -> 0x3C/0x00 byte array (coalesced stream) ----------------
__global__ void kmask(const int4* __restrict__ adj4, unsigned* __restrict__ mw) {
    int w0 = blockIdx.x * 4 + (threadIdx.x >> 6);     // wave id, 16384 total
    int lane = threadIdx.x & 63;
#pragma unroll
    for (int it = 0; it < 4; it++) {
        size_t g = (size_t)w0 * 4 + it;               // 65536 groups of 256 ints
        int4 v = adj4[g * 64 + lane];
        unsigned b0 = v.x ? 0x3Cu : 0u, b1 = v.y ? 0x3Cu : 0u;
        unsigned b2 = v.z ? 0x3Cu : 0u, b3 = v.w ? 0x3Cu : 0u;
        mw[g * 64 + lane] = b0 | (b1 << 8) | (b2 << 16) | (b3 << 24);
    }
}

// ---- kbit (fallback): adj -> u64 bitmask via ballot -----------------------
__global__ void kbit(const int* __restrict__ adj, unsigned long long* __restrict__ bm) {
    int wid = blockIdx.x * 4 + (threadIdx.x >> 6);
    int lane = threadIdx.x & 63;
    size_t base = (size_t)wid * 16;
#pragma unroll
    for (int s = 0; s < 16; s++) {
        size_t strip = base + s;
        int v = adj[strip * 64 + lane];
        unsigned long long m = __ballot(v != 0);
        if (lane == 0) bm[strip] = m;
    }
}

// ---- k12: Wh (MFMA) + fused s1/s2/U/V epilogue ----------------------------
// 1024 blocks = b*256 + it*2 + hh; wave covers 1 head (hh*4+w), 16 n rows.
__global__ __launch_bounds__(256) void k12(const float* __restrict__ x,
                                           const unsigned short* __restrict__ WTbf,
                                           const float* __restrict__ AF,
                                           _Float16* __restrict__ WHH,
                                           float* __restrict__ S1,
                                           _Float16* __restrict__ UH,
                                           _Float16* __restrict__ VH) {
    int bid = blockIdx.x;
    int hh = bid & 1;
    int it = (bid >> 1) & 127;
    int b  = bid >> 8;
    int n0 = it * 16;
    int wave = threadIdx.x >> 6, lane = threadIdx.x & 63;
    int lm = lane & 15, lq = lane >> 4;
    int h = hh * 4 + wave;
    int bh = b * H + h;
    const float* xr = x + (size_t)(b * N + n0 + lm) * F;
    f32x4 acc[2] = {};
#pragma unroll
    for (int kc = 0; kc < 8; kc++) {
        int k0f = kc * 32 + lq * 8;
        f32x4 xa = *(const f32x4*)(xr + k0f);
        f32x4 xb = *(const f32x4*)(xr + k0f + 4);
        union { short8 s; unsigned u[4]; } af;
        af.u[0] = pk_rne(xa[0], xa[1]);
        af.u[1] = pk_rne(xa[2], xa[3]);
        af.u[2] = pk_rne(xb[0], xb[1]);
        af.u[3] = pk_rne(xb[2], xb[3]);
#pragma unroll
        for (int c = 0; c < 2; c++) {
            int hd = h * 32 + c * 16 + lm;
            short8 bf = *(const short8*)(WTbf + hd * F + k0f);
            acc[c] = __builtin_amdgcn_mfma_f32_16x16x32_bf16(af.s, bf, acc[c], 0, 0, 0);
        }
    }
    // epilogue: WHH f16 + s1/s2 reduced over d (=lm groups)
    float a1l = AF[h * 64 + lm],      a1h = AF[h * 64 + 16 + lm];
    float a2l = AF[h * 64 + 32 + lm], a2h = AF[h * 64 + 48 + lm];
    float s1v[4], s2v[4];
#pragma unroll
    for (int r = 0; r < 4; r++) {
        int n = n0 + lq * 4 + r;                      // D[m=lq*4+r][hd col=lm]
        WHH[((size_t)bh * D + lm) * N + n] = (_Float16)acc[0][r];
        WHH[((size_t)bh * D + 16 + lm) * N + n] = (_Float16)acc[1][r];
        float s1p = acc[0][r] * a1l + acc[1][r] * a1h;
        float s2p = acc[0][r] * a2l + acc[1][r] * a2h;
#pragma unroll
        for (int off = 1; off <= 8; off <<= 1) {      // reduce over lm within 16
            s1p += __shfl_xor(s1p, off);
            s2p += __shfl_xor(s2p, off);
        }
        s1v[r] = s1p; s2v[r] = s2p;
    }
    if (lm == 0) {
        int nb = n0 + lq * 4;
#pragma unroll
        for (int r = 0; r < 4; r++) {
            S1[(size_t)bh * N + nb + r] = s1v[r];
            UH[(size_t)bh * N + nb + r] = (_Float16)exp2f(C1 * s2v[r]);
            VH[(size_t)bh * N + nb + r] = (_Float16)exp2f(C2 * s2v[r]);
        }
    }
}

// ---- k3: softmax+PV, f16 packed math, j-split waves, LDS combine ----------
// 2048 blocks = b*512 + it*4 + hp; wave (h2,jh): head hp*2+h2, j-half jh.
template <int MBYTE>
__global__ __launch_bounds__(256) void k3_attn(
    const unsigned char* __restrict__ mskb, const unsigned long long* __restrict__ bmw,
    const _Float16* __restrict__ WHH, const float* __restrict__ S1,
    const _Float16* __restrict__ UH, const _Float16* __restrict__ VH,
    float* __restrict__ out) {
    __shared__ f32x4 xch[2][3][64];
    int bid = blockIdx.x;
    int hp = bid & 3;
    int it = (bid >> 2) & 127;
    int b  = bid >> 9;
    int i0 = it * 16;
    int lane = threadIdx.x & 63, wave = threadIdx.x >> 6;
    int h2 = wave >> 1, jh = wave & 1;
    int h = hp * 2 + h2;
    int bh = b * H + h;
    int irow = lane & 15, quad = lane >> 4;

    float s1i = S1[(size_t)bh * N + i0 + irow];
    _Float16 cih = (_Float16)exp2f((C2 - C1) * s1i);  // e^{(alpha-1)*s1}
    unsigned short cw = __builtin_bit_cast(unsigned short, cih);
    unsigned ci2 = (unsigned)cw | ((unsigned)cw << 16);

    const _Float16* up  = UH + (size_t)bh * N + jh * 1024;
    const _Float16* vp  = VH + (size_t)bh * N + jh * 1024;
    const _Float16* wb0 = WHH + ((size_t)bh * D + irow) * N + jh * 1024;
    const _Float16* wb1 = wb0 + (size_t)16 * N;
    const unsigned char* mrow = mskb + ((size_t)(b * N + i0 + irow)) * N + jh * 1024;
    const unsigned long long* brow = bmw + (size_t)(b * N + i0 + irow) * 32 + jh * 16;

    union { h8 v; unsigned u[4]; } ones;
    ones.u[0] = ones.u[1] = ones.u[2] = ones.u[3] = 0x3C003C00u;  // f16 1.0 x8

    f32x4 acc0 = {0.f, 0.f, 0.f, 0.f};
    f32x4 acc1 = {0.f, 0.f, 0.f, 0.f};
    f32x4 accL = {0.f, 0.f, 0.f, 0.f};
    for (int jb = 0; jb < 1024; jb += 64) {
        unsigned long long wq = MBYTE ? 0ull : brow[jb >> 6];
#pragma unroll
        for (int g = 0; g < 2; g++) {
            int jo = jb + g * 32 + quad * 8;
            uint4 uw = *(const uint4*)(up + jo);
            uint4 vw = *(const uint4*)(vp + jo);
            unsigned m0, m1, m2, m3;
            if (MBYTE) {
                uint2 mb = *(const uint2*)(mrow + jo);
                m0 = __builtin_amdgcn_perm(0u, mb.x, 0x01040004u);  // bytes0,1 -> f16 hi-bytes
                m1 = __builtin_amdgcn_perm(0u, mb.x, 0x03040204u);  // bytes2,3
                m2 = __builtin_amdgcn_perm(0u, mb.y, 0x01040004u);
                m3 = __builtin_amdgcn_perm(0u, mb.y, 0x03040204u);
            } else {
                unsigned mk = (unsigned)(wq >> (g * 32 + quad * 8));
                m0 = ((mk & 1u) ? 0x3C00u : 0u) | ((mk & 2u) ? 0x3C000000u : 0u);
                m1 = ((mk & 4u) ? 0x3C00u : 0u) | ((mk & 8u) ? 0x3C000000u : 0u);
                m2 = ((mk & 16u) ? 0x3C00u : 0u) | ((mk & 32u) ? 0x3C000000u : 0u);
                m3 = ((mk & 64u) ? 0x3C00u : 0u) | ((mk & 128u) ? 0x3C000000u : 0u);
            }
            union { h8 v; unsigned u[4]; } af;
            af.u[0] = h2mul(h2max(uw.x, h2mul(ci2, vw.x)), m0);   // p' = max(u, ci*v) * mask
            af.u[1] = h2mul(h2max(uw.y, h2mul(ci2, vw.y)), m1);
            af.u[2] = h2mul(h2max(uw.z, h2mul(ci2, vw.z)), m2);
            af.u[3] = h2mul(h2max(uw.w, h2mul(ci2, vw.w)), m3);
            h8 bf0 = *(const h8*)(wb0 + jo);
            h8 bf1 = *(const h8*)(wb1 + jo);
            acc0 = __builtin_amdgcn_mfma_f32_16x16x32_f16(af.v, bf0, acc0, 0, 0, 0);
            acc1 = __builtin_amdgcn_mfma_f32_16x16x32_f16(af.v, bf1, acc1, 0, 0, 0);
            accL = __builtin_amdgcn_mfma_f32_16x16x32_f16(af.v, ones.v, accL, 0, 0, 0);
        }
    }
    if (jh == 1) {
        xch[h2][0][lane] = acc0;
        xch[h2][1][lane] = acc1;
        xch[h2][2][lane] = accL;
    }
    __syncthreads();
    if (jh == 0) {
        acc0 += xch[h2][0][lane];
        acc1 += xch[h2][1][lane];
        accL += xch[h2][2][lane];
#pragma unroll
        for (int r = 0; r < 4; r++) {
            float lr = accL[r];
            float rin = 1.0f / (lr > 0.f ? lr : 1.f);
            float v0 = acc0[r] * rin;
            float v1 = acc1[r] * rin;
            v0 = v0 > 0.f ? v0 : __expf(v0) - 1.f;     // ELU
            v1 = v1 > 0.f ? v1 : __expf(v1) - 1.f;
            size_t rowb = (size_t)(b * N + i0 + quad * 4 + r) * (H * D) + h * D;
            out[rowb + irow] = v0;
            out[rowb + 16 + irow] = v1;
        }
    }
}

extern "C" void kernel_launch(void* const* d_in, const int* in_sizes, int n_in,
                              void* d_out, int out_size, void* d_ws, size_t ws_size,
                              hipStream_t stream) {
    const void *xP = nullptr, *adjP = nullptr, *WP = nullptr, *aP = nullptr;
    for (int i = 0; i < n_in; i++) {
        switch (in_sizes[i]) {
            case SZ_X:   xP = d_in[i]; break;
            case SZ_ADJ: adjP = d_in[i]; break;
            case SZ_W:   WP = d_in[i]; break;
            case SZ_A:   aP = d_in[i]; break;
            default: break;
        }
    }
    if (!xP || !adjP || !WP || !aP) { xP = d_in[0]; adjP = d_in[1]; WP = d_in[2]; aP = d_in[3]; }
    float* out = (float*)d_out;

    char* ws = (char*)d_ws;
    unsigned short* WTbf = (unsigned short*)(ws);
    float* AF  = (float*)(ws + 131072);
    float* S1  = (float*)(ws + 133120);
    _Float16* UH = (_Float16*)(ws + 395264);
    _Float16* VH = (_Float16*)(ws + 526336);
    _Float16* WHH = (_Float16*)(ws + 657408);
    unsigned char* MSK = (unsigned char*)(ws + 4851712);
    unsigned long long* BM = (unsigned long long*)(ws + 4851712);

    int useByte = (ws_size >= (size_t)4851712 + 16777216) ? 1 : 0;

    k0_prep<<<256, 256, 0, stream>>>((const float*)WP, (const float*)aP, WTbf, AF);
    if (useByte) kmask<<<4096, 256, 0, stream>>>((const int4*)adjP, (unsigned*)MSK);
    else         kbit<<<4096, 256, 0, stream>>>((const int*)adjP, BM);
    k12<<<1024, 256, 0, stream>>>((const float*)xP, WTbf, AF, WHH, S1, UH, VH);
    if (useByte) k3_attn<1><<<2048, 256, 0, stream>>>(MSK, BM, WHH, S1, UH, VH, out);
    else         k3_attn<0><<<2048, 256, 0, stream>>>(MSK, BM, WHH, S1, UH, VH, out);
}

// Round 12
// 164.468 us; speedup vs baseline: 1.5705x; 1.3650x over previous
//
#include <hip/hip_runtime.h>
#include <hip/hip_bf16.h>

#define ALPHA 0.2f

typedef __attribute__((ext_vector_type(8))) short short8;
typedef __attribute__((ext_vector_type(8))) _Float16 h8;
typedef __attribute__((ext_vector_type(2))) _Float16 h2v;
typedef __attribute__((ext_vector_type(4))) float f32x4;

static constexpr int B = 4, N = 2048, F = 256, H = 8, D = 32;
static constexpr int SZ_X = B * N * F, SZ_ADJ = B * N * N, SZ_W = H * F * D, SZ_A = H * 2 * D;
static const float C1 = 1.4426950408889634f;           // log2(e)
static const float C2 = ALPHA * 1.4426950408889634f;

// ws layout (bytes):
// 0        WTbf bf16 [hd=256][f=256]  131072
// 131072   AF   f32  [H][64]          2048
// 133120   S1   f32  [32][2048]       262144
// 395264   UH   f16  [32][2048]       131072
// 526336   VH   f16  [32][2048]       131072
// 657408   WHT  f16  [b][hd=256][n=2048] 4194304
// 4851712  BM   u64  [B*N*N/64]       2097152   total ~6.6 MB

__device__ __forceinline__ unsigned rne16(unsigned u) {
    return u + 0x7fffu + ((u >> 16) & 1u);
}
__device__ __forceinline__ unsigned pk_rne(float a, float b) {   // bf16 pair
    return __builtin_amdgcn_perm(rne16(__float_as_uint(b)),
                                 rne16(__float_as_uint(a)), 0x07060302u);
}
__device__ __forceinline__ unsigned h2mul(unsigned a, unsigned b) {
    h2v r = __builtin_bit_cast(h2v, a) * __builtin_bit_cast(h2v, b);
    return __builtin_bit_cast(unsigned, r);
}
__device__ __forceinline__ unsigned h2max(unsigned a, unsigned b) {
    h2v r = __builtin_elementwise_max(__builtin_bit_cast(h2v, a),
                                      __builtin_bit_cast(h2v, b));
    return __builtin_bit_cast(unsigned, r);
}

// ---- k0: W[h][f][d] -> WTbf[hd][f] bf16; a -> AF --------------------------
__global__ void k0_prep(const float* __restrict__ Wp, const float* __restrict__ ap,
                        unsigned short* __restrict__ WTbf, float* __restrict__ AF) {
    int bid = blockIdx.x;              // 256 = H*D
    int h = bid >> 5, d = bid & 31;
    int f = threadIdx.x;
    WTbf[(h * D + d) * F + f] =
        (unsigned short)(rne16(__float_as_uint(Wp[(h * F + f) * D + d])) >> 16);
    if (d == 0 && f < 64) AF[h * 64 + f] = ap[h * 64 + f];
}

// ---- kbit: adj -> u64 bitmask via ballot (coalesced stream) ---------------
__global__ void kbit(const int* __restrict__ adj, unsigned long long* __restrict__ bm) {
    int wid = blockIdx.x * 4 + (threadIdx.x >> 6);   // 4096 blocks
    int lane = threadIdx.x & 63;
    size_t base = (size_t)wid * 16;
#pragma unroll
    for (int s = 0; s < 16; s++) {
        size_t strip = base + s;
        int v = adj[strip * 64 + lane];
        unsigned long long m = __ballot(v != 0);
        if (lane == 0) bm[strip] = m;
    }
}

// ---- k12: LDS-tiled MFMA Wh + fused s1/s2/U/V epilogue --------------------
// 512 blocks = b*128 + 16-n tile; 4 waves, wave w -> hd in [w*64, w*64+64)
__global__ __launch_bounds__(256) void k12(const float* __restrict__ x,
                                           const unsigned short* __restrict__ WTbf,
                                           const float* __restrict__ AF,
                                           unsigned short* __restrict__ WHT,
                                           float* __restrict__ S1,
                                           _Float16* __restrict__ UH,
                                           _Float16* __restrict__ VH) {
    __shared__ unsigned short XA[16 * 264];   // [n][f] bf16, pad 264
    __shared__ unsigned short WB[256 * 40];   // [hd][32 f chunk] bf16, pad 40
    int bid = blockIdx.x;
    int b = bid >> 7;
    int n0 = (bid & 127) * 16;
    int t = threadIdx.x;
    int wave = t >> 6, lane = t & 63;
    int lm = lane & 15, lq = lane >> 4;

    // stage XA coalesced: 1024 16B-chunks of x fp32 -> bf16
#pragma unroll
    for (int q = 0; q < 4; q++) {
        int idx = q * 256 + t;
        int row = idx >> 6, c16 = idx & 63;
        f32x4 v = *(const f32x4*)(x + (size_t)(b * N + n0 + row) * F + c16 * 4);
        unsigned* dst = (unsigned*)&XA[row * 264 + c16 * 4];
        dst[0] = pk_rne(v[0], v[1]);
        dst[1] = pk_rne(v[2], v[3]);
    }

    f32x4 acc[4] = {};
    for (int kc = 0; kc < 8; kc++) {
        __syncthreads();
        // stage WB coalesced: WTbf[256 hd][kc*32..+32]
#pragma unroll
        for (int q = 0; q < 4; q++) {
            int idx = q * 256 + t;
            int row = idx >> 2, c = idx & 3;
            short8 w = *(const short8*)(WTbf + row * 256 + kc * 32 + c * 8);
            *(short8*)&WB[row * 40 + c * 8] = w;
        }
        __syncthreads();
        short8 afr = *(const short8*)&XA[lm * 264 + kc * 32 + lq * 8];
#pragma unroll
        for (int c = 0; c < 4; c++) {
            short8 bfr = *(const short8*)&WB[(wave * 64 + c * 16 + lm) * 40 + lq * 8];
            acc[c] = __builtin_amdgcn_mfma_f32_16x16x32_bf16(afr, bfr, acc[c], 0, 0, 0);
        }
    }

    // epilogue 1: WHT[b][hd][n] f16, 8B packed stores
#pragma unroll
    for (int c = 0; c < 4; c++) {
        int hd = wave * 64 + c * 16 + lm;
        unsigned short w0 = __builtin_bit_cast(unsigned short, (_Float16)acc[c][0]);
        unsigned short w1 = __builtin_bit_cast(unsigned short, (_Float16)acc[c][1]);
        unsigned short w2 = __builtin_bit_cast(unsigned short, (_Float16)acc[c][2]);
        unsigned short w3 = __builtin_bit_cast(unsigned short, (_Float16)acc[c][3]);
        uint2 pk;
        pk.x = (unsigned)w0 | ((unsigned)w1 << 16);
        pk.y = (unsigned)w2 | ((unsigned)w3 << 16);
        *(uint2*)&WHT[((size_t)b * 256 + hd) * 2048 + n0 + lq * 4] = pk;
    }
    // epilogue 2: s1/s2 per (head, n); reduce over d (lm lanes + c-pair)
#pragma unroll
    for (int cp = 0; cp < 2; cp++) {
        int h = wave * 2 + cp;
        float a1l = AF[h * 64 + lm],      a1h = AF[h * 64 + 16 + lm];
        float a2l = AF[h * 64 + 32 + lm], a2h = AF[h * 64 + 48 + lm];
#pragma unroll
        for (int r = 0; r < 4; r++) {
            float s1p = acc[cp * 2][r] * a1l + acc[cp * 2 + 1][r] * a1h;
            float s2p = acc[cp * 2][r] * a2l + acc[cp * 2 + 1][r] * a2h;
#pragma unroll
            for (int off = 1; off <= 8; off <<= 1) {
                s1p += __shfl_xor(s1p, off);
                s2p += __shfl_xor(s2p, off);
            }
            if (lm == 0) {
                int bh = b * 8 + h, n = n0 + lq * 4 + r;
                S1[(size_t)bh * 2048 + n] = s1p;
                UH[(size_t)bh * 2048 + n] = (_Float16)exp2f(C1 * s2p);
                VH[(size_t)bh * 2048 + n] = (_Float16)exp2f(C2 * s2p);
            }
        }
    }
}

// ---- k3: LDS-staged softmax+PV; block = (b, 16-i tile), 8 waves = 8 heads -
__global__ __launch_bounds__(512) void k3_attn(
    const unsigned* __restrict__ bm32,
    const unsigned short* __restrict__ WHT,
    const float* __restrict__ S1,
    const _Float16* __restrict__ UH, const _Float16* __restrict__ VH,
    float* __restrict__ out) {
    __shared__ unsigned short LW[256 * 136];  // [hd][128 j chunk], pad 136
    __shared__ unsigned LM[16 * 66];          // [i][j-word], pad 66
    __shared__ unsigned short LU[8 * 128];    // [h][128 j]
    __shared__ unsigned short LV[8 * 128];

    int bid = blockIdx.x;                     // 512 = b*128 + it
    int b = bid >> 7;
    int i0 = (bid & 127) * 16;
    int t = threadIdx.x;
    int wave = t >> 6, lane = t & 63;
    int h = wave;                             // 8 waves = 8 heads
    int bh = b * 8 + h;
    int irow = lane & 15, quad = lane >> 4;

    // stage mask bits once: 16 rows x 64 words, coalesced
    {
        int row = t >> 5, w0 = (t & 31) * 2;
        uint2 mv = *(const uint2*)(bm32 + ((size_t)(b * N + i0 + row)) * 64 + w0);
        LM[row * 66 + w0] = mv.x;
        LM[row * 66 + w0 + 1] = mv.y;
    }

    float s1i = S1[(size_t)bh * N + i0 + irow];
    unsigned short cw = __builtin_bit_cast(unsigned short, (_Float16)exp2f((C2 - C1) * s1i));
    unsigned ci2 = (unsigned)cw | ((unsigned)cw << 16);

    union { h8 v; unsigned u[4]; } ones;
    ones.u[0] = ones.u[1] = ones.u[2] = ones.u[3] = 0x3C003C00u;

    f32x4 acc0 = {0.f, 0.f, 0.f, 0.f};
    f32x4 acc1 = {0.f, 0.f, 0.f, 0.f};
    f32x4 accL = {0.f, 0.f, 0.f, 0.f};

    for (int cc = 0; cc < 16; cc++) {
        __syncthreads();
        // stage LW coalesced: 256 rows x 256B (j-chunk of 128)
        const unsigned short* src = WHT + (size_t)b * 256 * 2048 + cc * 128;
#pragma unroll
        for (int q = 0; q < 8; q++) {
            int idx = q * 512 + t;                 // 4096 16B units
            int row = idx >> 4, u = idx & 15;
            short8 v = *(const short8*)(src + (size_t)row * 2048 + u * 8);
            *(short8*)&LW[row * 136 + u * 8] = v;
        }
        // stage LU/LV: 8 heads x 128 j each
        if (t < 256) {
            int which = t >> 7;
            int hh = (t & 127) >> 4, u16 = t & 15;
            const _Float16* s = (which ? VH : UH) + (size_t)(b * 8 + hh) * 2048 + cc * 128 + u16 * 8;
            short8 v = *(const short8*)s;
            unsigned short* dst = which ? LV : LU;
            *(short8*)&dst[hh * 128 + u16 * 8] = v;
        }
        __syncthreads();
        // compute: 4 groups of 32 j, all from LDS
#pragma unroll
        for (int g = 0; g < 4; g++) {
            unsigned mk = LM[irow * 66 + cc * 4 + g] >> (quad * 8);
            int jl = g * 32 + quad * 8;
            uint4 uw = *(const uint4*)&LU[h * 128 + jl];
            uint4 vw = *(const uint4*)&LV[h * 128 + jl];
            unsigned m0 = ((mk & 1u)   ? 0x3C00u : 0u) | ((mk & 2u)   ? 0x3C000000u : 0u);
            unsigned m1 = ((mk & 4u)   ? 0x3C00u : 0u) | ((mk & 8u)   ? 0x3C000000u : 0u);
            unsigned m2 = ((mk & 16u)  ? 0x3C00u : 0u) | ((mk & 32u)  ? 0x3C000000u : 0u);
            unsigned m3 = ((mk & 64u)  ? 0x3C00u : 0u) | ((mk & 128u) ? 0x3C000000u : 0u);
            union { h8 v; unsigned u[4]; } af;
            af.u[0] = h2mul(h2max(uw.x, h2mul(ci2, vw.x)), m0);
            af.u[1] = h2mul(h2max(uw.y, h2mul(ci2, vw.y)), m1);
            af.u[2] = h2mul(h2max(uw.z, h2mul(ci2, vw.z)), m2);
            af.u[3] = h2mul(h2max(uw.w, h2mul(ci2, vw.w)), m3);
            h8 bf0 = *(const h8*)&LW[(h * 32 + irow) * 136 + jl];
            h8 bf1 = *(const h8*)&LW[(h * 32 + 16 + irow) * 136 + jl];
            acc0 = __builtin_amdgcn_mfma_f32_16x16x32_f16(af.v, bf0, acc0, 0, 0, 0);
            acc1 = __builtin_amdgcn_mfma_f32_16x16x32_f16(af.v, bf1, acc1, 0, 0, 0);
            accL = __builtin_amdgcn_mfma_f32_16x16x32_f16(af.v, ones.v, accL, 0, 0, 0);
        }
    }
#pragma unroll
    for (int r = 0; r < 4; r++) {
        float lr = accL[r];
        float rin = 1.0f / (lr > 0.f ? lr : 1.f);
        float v0 = acc0[r] * rin;
        float v1 = acc1[r] * rin;
        v0 = v0 > 0.f ? v0 : __expf(v0) - 1.f;     // ELU
        v1 = v1 > 0.f ? v1 : __expf(v1) - 1.f;
        size_t rowb = (size_t)(b * N + i0 + quad * 4 + r) * (H * D) + h * D;
        out[rowb + irow] = v0;
        out[rowb + 16 + irow] = v1;
    }
}

extern "C" void kernel_launch(void* const* d_in, const int* in_sizes, int n_in,
                              void* d_out, int out_size, void* d_ws, size_t ws_size,
                              hipStream_t stream) {
    const void *xP = nullptr, *adjP = nullptr, *WP = nullptr, *aP = nullptr;
    for (int i = 0; i < n_in; i++) {
        switch (in_sizes[i]) {
            case SZ_X:   xP = d_in[i]; break;
            case SZ_ADJ: adjP = d_in[i]; break;
            case SZ_W:   WP = d_in[i]; break;
            case SZ_A:   aP = d_in[i]; break;
            default: break;
        }
    }
    if (!xP || !adjP || !WP || !aP) { xP = d_in[0]; adjP = d_in[1]; WP = d_in[2]; aP = d_in[3]; }
    float* out = (float*)d_out;

    char* ws = (char*)d_ws;
    unsigned short* WTbf = (unsigned short*)(ws);
    float* AF  = (float*)(ws + 131072);
    float* S1  = (float*)(ws + 133120);
    _Float16* UH = (_Float16*)(ws + 395264);
    _Float16* VH = (_Float16*)(ws + 526336);
    unsigned short* WHT = (unsigned short*)(ws + 657408);
    unsigned long long* BM = (unsigned long long*)(ws + 4851712);

    k0_prep<<<256, 256, 0, stream>>>((const float*)WP, (const float*)aP, WTbf, AF);
    kbit<<<4096, 256, 0, stream>>>((const int*)adjP, BM);
    k12<<<512, 256, 0, stream>>>((const float*)xP, WTbf, AF, WHT, S1, UH, VH);
    k3_attn<<<512, 512, 0, stream>>>((const unsigned*)BM, WHT, S1, UH, VH, out);
}